// Round 4
// baseline (108.103 us; speedup 1.0000x reference)
//
#include <hip/hip_runtime.h>
#include <stdint.h>

typedef __attribute__((ext_vector_type(8))) _Float16 half8;
typedef __attribute__((ext_vector_type(16))) float f32x16;

#define NPTS 131072
#define NTGT 16384
#define NJT (NTGT / 32)            // 512 j-tiles of 32 targets
#define JSPLIT 2                   // target-range split across blockIdx.y
#define JT_PER (NJT / JSPLIT)      // 256 j-tiles per block
#define STAGE_JT 16                // j-tiles per LDS stage
#define NSTAGE (JT_PER / STAGE_JT) // 16
#define STAGE_BYTES (STAGE_JT * 1024)  // 16 KB

#define SPLIT_S 512.0f
#define INV_S (1.0f / 512.0f)

// ---------- prep: pack each target into two 16B B-fragments --------------
__global__ __launch_bounds__(256) void cpl_prep(const float* __restrict__ targets,
                                                half8* __restrict__ bfrag) {
  const int j = blockIdx.x * 256 + threadIdx.x;
  if (j >= NTGT) return;
  const float tx = targets[3 * j + 0], ty = targets[3 * j + 1], tz = targets[3 * j + 2];
  const float t2 = fmaf(tx, tx, fmaf(ty, ty, tz * tz));
  const _Float16 txh = (_Float16)tx; const float txl = tx - (float)txh;
  const _Float16 tyh = (_Float16)ty; const float tyl = ty - (float)tyh;
  const _Float16 tzh = (_Float16)tz; const float tzl = tz - (float)tzh;
  const _Float16 t2h = (_Float16)t2; const float t2l = t2 - (float)t2h;
  half8 blo, bhi;
  blo[0] = -txh; blo[1] = (_Float16)(-(float)txh * INV_S); blo[2] = (_Float16)(-txl * SPLIT_S);
  blo[3] = -tyh; blo[4] = (_Float16)(-(float)tyh * INV_S); blo[5] = (_Float16)(-tyl * SPLIT_S);
  blo[6] = -tzh; blo[7] = (_Float16)(-(float)tzh * INV_S);
  bhi[0] = (_Float16)(-tzl * SPLIT_S);
  bhi[1] = (_Float16)1.0f; bhi[2] = (_Float16)INV_S;
  bhi[3] = t2h;            bhi[4] = (_Float16)(t2l * SPLIT_S);
  bhi[5] = (_Float16)0.0f; bhi[6] = (_Float16)0.0f; bhi[7] = (_Float16)0.0f;
  const int jt = j >> 5, jj = j & 31;
  bfrag[jt * 64 + jj] = blo;
  bfrag[jt * 64 + 32 + jj] = bhi;
}

// ---------- A-fragment builder (per lane, per point) ----------------------
__device__ __forceinline__ half8 make_afrag(const float* __restrict__ o, int p, int hi) {
  const float sx = 2.0f * o[3 * p + 0], sy = 2.0f * o[3 * p + 1], sz = 2.0f * o[3 * p + 2];
  const float o2 = 0.25f * fmaf(sx, sx, fmaf(sy, sy, sz * sz));
  const _Float16 xh = (_Float16)sx; const float xl = sx - (float)xh;
  const _Float16 yh = (_Float16)sy; const float yl = sy - (float)yh;
  const _Float16 zh = (_Float16)sz; const float zl = sz - (float)zh;
  const _Float16 qh = (_Float16)o2; const float ql = o2 - (float)qh;
  half8 lo, hi8;
  lo[0] = xh; lo[1] = (_Float16)(xl * SPLIT_S); lo[2] = (_Float16)((float)xh * INV_S);
  lo[3] = yh; lo[4] = (_Float16)(yl * SPLIT_S); lo[5] = (_Float16)((float)yh * INV_S);
  lo[6] = zh; lo[7] = (_Float16)(zl * SPLIT_S);
  hi8[0] = (_Float16)((float)zh * INV_S);
  hi8[1] = qh;             hi8[2] = (_Float16)(ql * SPLIT_S);
  hi8[3] = (_Float16)1.0f; hi8[4] = (_Float16)INV_S;
  hi8[5] = (_Float16)0.0f; hi8[6] = (_Float16)0.0f; hi8[7] = (_Float16)0.0f;
  return hi ? hi8 : lo;
}

__device__ __forceinline__ void gload16(const void* g, void* l) {
  __builtin_amdgcn_global_load_lds(
      (const __attribute__((address_space(1))) uint32_t*)g,
      (__attribute__((address_space(3))) uint32_t*)l, 16, 0, 0);
}

// Single-instruction 3-input min (IEEE mode blocks the compiler's own fusion).
__device__ __forceinline__ float fmin3(float a, float b, float c) {
  float d;
  asm("v_min3_f32 %0, %1, %2, %3" : "=v"(d) : "v"(a), "v"(b), "v"(c));
  return d;
}

// ---------- main: wave owns 2 point-tiles (64 pts) x half the targets -----
__global__ __launch_bounds__(256) void cpl_main(const float* __restrict__ outputs,
                                                const char* __restrict__ bfrag_b,
                                                float* __restrict__ wsmin) {
  __shared__ __align__(16) char smem[2][STAGE_BYTES];
  const int tid = threadIdx.x;
  const int lane = tid & 63;
  const int w = tid >> 6;
  const int hi = lane >> 5;
  const int gw = blockIdx.x * 4 + w;       // point-wave id (0..2047)
  const int jtbase = blockIdx.y * JT_PER;  // target half

  const int prow = lane & 31;
  const half8 a0 = make_afrag(outputs, gw * 64 + prow, hi);
  const half8 a1 = make_afrag(outputs, gw * 64 + 32 + prow, hi);

  f32x16 mn0, mn1, zed;
#pragma unroll
  for (int r = 0; r < 16; ++r) { zed[r] = 0.0f; mn0[r] = 3.0e38f; mn1[r] = 3.0e38f; }

  auto stage = [&](int s, int b) {
    const char* gbase = bfrag_b + (size_t)(jtbase + s * STAGE_JT) * 1024 + w * 4096 + lane * 16;
    char* lbase = &smem[b][w * 4096];
#pragma unroll
    for (int c = 0; c < 4; ++c) gload16(gbase + c * 1024, lbase + c * 1024);
  };

  stage(0, 0);
  int buf = 0;
  for (int s = 0; s < NSTAGE; ++s) {
    __syncthreads();  // drains this stage's loads; protects buffer reuse
    if (s + 1 < NSTAGE) stage(s + 1, buf ^ 1);
#pragma unroll
    for (int jp = 0; jp < STAGE_JT / 2; ++jp) {
      const half8 b0 = *(const half8*)&smem[buf][(2 * jp + 0) * 1024 + lane * 16];
      const half8 b1 = *(const half8*)&smem[buf][(2 * jp + 1) * 1024 + lane * 16];
      f32x16 p0 = __builtin_amdgcn_mfma_f32_32x32x16_f16(a0, b0, zed, 0, 0, 0);
      f32x16 p1 = __builtin_amdgcn_mfma_f32_32x32x16_f16(a0, b1, zed, 0, 0, 0);
      f32x16 q0 = __builtin_amdgcn_mfma_f32_32x32x16_f16(a1, b0, zed, 0, 0, 0);
      f32x16 q1 = __builtin_amdgcn_mfma_f32_32x32x16_f16(a1, b1, zed, 0, 0, 0);
#pragma unroll
      for (int r = 0; r < 16; ++r) mn0[r] = fmin3(p0[r], p1[r], mn0[r]);
#pragma unroll
      for (int r = 0; r < 16; ++r) mn1[r] = fmin3(q0[r], q1[r], mn1[r]);
    }
    buf ^= 1;
  }

  // Min across the 32 target-columns: butterfly within each 32-lane half.
#pragma unroll
  for (int r = 0; r < 16; ++r) {
    float v0 = mn0[r], v1 = mn1[r];
#pragma unroll
    for (int m = 1; m <= 16; m <<= 1) {
      v0 = fminf(v0, __shfl_xor(v0, m, 64));
      v1 = fminf(v1, __shfl_xor(v1, m, 64));
    }
    mn0[r] = v0; mn1[r] = v1;
  }

  // Designated lane of each half writes its 32 rows' candidate mins.
  if ((lane & 31) == 0) {
    float* wsA = wsmin + (size_t)blockIdx.y * NPTS + gw * 64;
#pragma unroll
    for (int r = 0; r < 16; ++r) {
      const int row = (r & 3) + 8 * (r >> 2) + 4 * hi;
      wsA[row] = mn0[r];
      wsA[32 + row] = mn1[r];
    }
  }
}

// ---------- reduce: per-point min over the 2 halves, then mean ------------
__global__ __launch_bounds__(256) void cpl_reduce1(const float* __restrict__ wsmin,
                                                   float* __restrict__ partial) {
  __shared__ float red[256];
  const int t = threadIdx.x;
  float s = 0.0f;
  for (int i = blockIdx.x * 256 + t; i < NPTS; i += 256 * 256)
    s += fminf(wsmin[i], wsmin[NPTS + i]);
  red[t] = s;
  __syncthreads();
  for (int off = 128; off > 0; off >>= 1) {
    if (t < off) red[t] += red[t + off];
    __syncthreads();
  }
  if (t == 0) partial[blockIdx.x] = red[0];
}

__global__ __launch_bounds__(256) void cpl_reduce2(const float* __restrict__ partial,
                                                   float* __restrict__ out) {
  __shared__ float red[256];
  const int t = threadIdx.x;
  red[t] = partial[t];
  __syncthreads();
  for (int off = 128; off > 0; off >>= 1) {
    if (t < off) red[t] += red[t + off];
    __syncthreads();
  }
  if (t == 0) out[0] = red[0] * (1.0f / (float)NPTS);
}

extern "C" void kernel_launch(void* const* d_in, const int* in_sizes, int n_in,
                              void* d_out, int out_size, void* d_ws, size_t ws_size,
                              hipStream_t stream) {
  const float* outputs = (const float*)d_in[0];  // [131072,3] f32
  const float* targets = (const float*)d_in[1];  // [16384,3] f32
  float* out = (float*)d_out;

  char* ws = (char*)d_ws;
  half8* bfrag = (half8*)ws;                                    // 512 KB
  float* wsmin = (float*)(ws + (size_t)512 * 1024);             // 2 x NPTS floats = 1 MB
  float* partial = (float*)(ws + (size_t)512 * 1024 + (size_t)2 * NPTS * 4);  // 256 floats

  cpl_prep<<<NTGT / 256, 256, 0, stream>>>(targets, bfrag);
  dim3 gmain(NPTS / 256, JSPLIT);  // 512 x 2 = 1024 blocks, 4096 waves
  cpl_main<<<gmain, 256, 0, stream>>>(outputs, (const char*)bfrag, wsmin);
  cpl_reduce1<<<256, 256, 0, stream>>>(wsmin, partial);
  cpl_reduce2<<<1, 256, 0, stream>>>(partial, out);
}

// Round 8
// 78.220 us; speedup vs baseline: 1.3820x; 1.3820x over previous
//
#include <hip/hip_runtime.h>
#include <stdint.h>

typedef __attribute__((ext_vector_type(8))) _Float16 half8;
typedef __attribute__((ext_vector_type(16))) float f32x16;

#define NPTS 131072
#define NTGT 16384
#define NJT (NTGT / 32)            // 512 j-tiles of 32 targets
#define JSPLIT 2                   // target-range split across blockIdx.y
#define JT_PER (NJT / JSPLIT)      // 256 j-tiles per y-slice
#define STAGE_JT 16                // j-tiles per LDS stage
#define NSTAGE (JT_PER / STAGE_JT) // 16
#define STAGE_BYTES (STAGE_JT * 1024)  // 16 KB

#define SPLIT_S 512.0f
#define INV_S (1.0f / 512.0f)

// ---------- prep: pack each target into two 16B B-fragments --------------
// (unchanged from the passing R3 kernel)
__global__ __launch_bounds__(256) void cpl_prep(const float* __restrict__ targets,
                                                half8* __restrict__ bfrag) {
  const int j = blockIdx.x * 256 + threadIdx.x;
  if (j >= NTGT) return;
  const float tx = targets[3 * j + 0], ty = targets[3 * j + 1], tz = targets[3 * j + 2];
  const float t2 = fmaf(tx, tx, fmaf(ty, ty, tz * tz));
  const _Float16 txh = (_Float16)tx; const float txl = tx - (float)txh;
  const _Float16 tyh = (_Float16)ty; const float tyl = ty - (float)tyh;
  const _Float16 tzh = (_Float16)tz; const float tzl = tz - (float)tzh;
  const _Float16 t2h = (_Float16)t2; const float t2l = t2 - (float)t2h;
  half8 blo, bhi;
  blo[0] = -txh; blo[1] = (_Float16)(-(float)txh * INV_S); blo[2] = (_Float16)(-txl * SPLIT_S);
  blo[3] = -tyh; blo[4] = (_Float16)(-(float)tyh * INV_S); blo[5] = (_Float16)(-tyl * SPLIT_S);
  blo[6] = -tzh; blo[7] = (_Float16)(-(float)tzh * INV_S);
  bhi[0] = (_Float16)(-tzl * SPLIT_S);
  bhi[1] = (_Float16)1.0f; bhi[2] = (_Float16)INV_S;
  bhi[3] = t2h;            bhi[4] = (_Float16)(t2l * SPLIT_S);
  bhi[5] = (_Float16)0.0f; bhi[6] = (_Float16)0.0f; bhi[7] = (_Float16)0.0f;
  const int jt = j >> 5, jj = j & 31;
  bfrag[jt * 64 + jj] = blo;
  bfrag[jt * 64 + 32 + jj] = bhi;
}

// ---------- A-fragment builder (unchanged from R3) ------------------------
__device__ __forceinline__ half8 make_afrag(const float* __restrict__ o, int p, int hi) {
  const float sx = 2.0f * o[3 * p + 0], sy = 2.0f * o[3 * p + 1], sz = 2.0f * o[3 * p + 2];
  const float o2 = 0.25f * fmaf(sx, sx, fmaf(sy, sy, sz * sz));
  const _Float16 xh = (_Float16)sx; const float xl = sx - (float)xh;
  const _Float16 yh = (_Float16)sy; const float yl = sy - (float)yh;
  const _Float16 zh = (_Float16)sz; const float zl = sz - (float)zh;
  const _Float16 qh = (_Float16)o2; const float ql = o2 - (float)qh;
  half8 lo, hi8;
  lo[0] = xh; lo[1] = (_Float16)(xl * SPLIT_S); lo[2] = (_Float16)((float)xh * INV_S);
  lo[3] = yh; lo[4] = (_Float16)(yl * SPLIT_S); lo[5] = (_Float16)((float)yh * INV_S);
  lo[6] = zh; lo[7] = (_Float16)(zl * SPLIT_S);
  hi8[0] = (_Float16)((float)zh * INV_S);
  hi8[1] = qh;             hi8[2] = (_Float16)(ql * SPLIT_S);
  hi8[3] = (_Float16)1.0f; hi8[4] = (_Float16)INV_S;
  hi8[5] = (_Float16)0.0f; hi8[6] = (_Float16)0.0f; hi8[7] = (_Float16)0.0f;
  return hi ? hi8 : lo;
}

__device__ __forceinline__ void gload16(const void* g, void* l) {
  __builtin_amdgcn_global_load_lds(
      (const __attribute__((address_space(1))) uint32_t*)g,
      (__attribute__((address_space(3))) uint32_t*)l, 16, 0, 0);
}

// ---------- main: wave owns 2 point-tiles (64 pts) x half the targets -----
// R8 change vs R3 (single variable): inner loop keeps only ONE f32x16 D-tuple
// live at a time (1 ds_read + 2 MFMA + 32 fminf per 32-target tile) so the
// ~75-reg live set avoids the AGPR cross-file shuffling that ate R3's cycles.
// No launch_bounds on this kernel: (256,2) miscompiled in R5/R6.
__global__ void cpl_main(const float* __restrict__ outputs,
                         const char* __restrict__ bfrag_b,
                         float* __restrict__ wsmin) {
  __shared__ __align__(16) char smem[2][STAGE_BYTES];
  const int tid = threadIdx.x;
  const int lane = tid & 63;
  const int w = tid >> 6;
  const int hi = lane >> 5;
  const int gw = blockIdx.x * 4 + w;       // point-wave id (0..2047)
  const int jtbase = blockIdx.y * JT_PER;  // target half

  const int prow = lane & 31;
  const half8 a0 = make_afrag(outputs, gw * 64 + prow, hi);
  const half8 a1 = make_afrag(outputs, gw * 64 + 32 + prow, hi);

  f32x16 mn0, mn1, zed;
#pragma unroll
  for (int r = 0; r < 16; ++r) { zed[r] = 0.0f; mn0[r] = 3.0e38f; mn1[r] = 3.0e38f; }

  auto stage = [&](int s, int b) {
    const char* gbase = bfrag_b + (size_t)(jtbase + s * STAGE_JT) * 1024 + w * 4096 + lane * 16;
    char* lbase = &smem[b][w * 4096];
#pragma unroll
    for (int c = 0; c < 4; ++c) gload16(gbase + c * 1024, lbase + c * 1024);
  };

  stage(0, 0);
  int buf = 0;
  for (int s = 0; s < NSTAGE; ++s) {
    __syncthreads();  // drains this stage's loads; protects buffer reuse
    if (s + 1 < NSTAGE) stage(s + 1, buf ^ 1);
#pragma unroll
    for (int jp = 0; jp < STAGE_JT; ++jp) {
      const half8 b = *(const half8*)&smem[buf][jp * 1024 + lane * 16];
      f32x16 d0 = __builtin_amdgcn_mfma_f32_32x32x16_f16(a0, b, zed, 0, 0, 0);
#pragma unroll
      for (int r = 0; r < 16; ++r) mn0[r] = fminf(mn0[r], d0[r]);
      f32x16 d1 = __builtin_amdgcn_mfma_f32_32x32x16_f16(a1, b, zed, 0, 0, 0);
#pragma unroll
      for (int r = 0; r < 16; ++r) mn1[r] = fminf(mn1[r], d1[r]);
    }
    buf ^= 1;
  }

  // Min across the 32 target-columns: butterfly within each 32-lane half.
#pragma unroll
  for (int r = 0; r < 16; ++r) {
    float v0 = mn0[r], v1 = mn1[r];
#pragma unroll
    for (int m = 1; m <= 16; m <<= 1) {
      v0 = fminf(v0, __shfl_xor(v0, m, 64));
      v1 = fminf(v1, __shfl_xor(v1, m, 64));
    }
    mn0[r] = v0; mn1[r] = v1;
  }

  // Designated lane of each half writes its 32 rows' candidate mins.
  if ((lane & 31) == 0) {
    float* wsA = wsmin + (size_t)blockIdx.y * NPTS + gw * 64;
#pragma unroll
    for (int r = 0; r < 16; ++r) {
      const int row = (r & 3) + 8 * (r >> 2) + 4 * hi;
      wsA[row] = mn0[r];
      wsA[32 + row] = mn1[r];
    }
  }
}

// ---------- reduce: per-point min over the 2 halves, then mean ------------
__global__ __launch_bounds__(256) void cpl_reduce1(const float* __restrict__ wsmin,
                                                   float* __restrict__ partial) {
  __shared__ float red[256];
  const int t = threadIdx.x;
  float s = 0.0f;
  for (int i = blockIdx.x * 256 + t; i < NPTS; i += 256 * 256)
    s += fminf(wsmin[i], wsmin[NPTS + i]);
  red[t] = s;
  __syncthreads();
  for (int off = 128; off > 0; off >>= 1) {
    if (t < off) red[t] += red[t + off];
    __syncthreads();
  }
  if (t == 0) partial[blockIdx.x] = red[0];
}

__global__ __launch_bounds__(256) void cpl_reduce2(const float* __restrict__ partial,
                                                   float* __restrict__ out) {
  __shared__ float red[256];
  const int t = threadIdx.x;
  red[t] = partial[t];
  __syncthreads();
  for (int off = 128; off > 0; off >>= 1) {
    if (t < off) red[t] += red[t + off];
    __syncthreads();
  }
  if (t == 0) out[0] = red[0] * (1.0f / (float)NPTS);
}

extern "C" void kernel_launch(void* const* d_in, const int* in_sizes, int n_in,
                              void* d_out, int out_size, void* d_ws, size_t ws_size,
                              hipStream_t stream) {
  const float* outputs = (const float*)d_in[0];  // [131072,3] f32
  const float* targets = (const float*)d_in[1];  // [16384,3] f32
  float* out = (float*)d_out;

  char* ws = (char*)d_ws;
  half8* bfrag = (half8*)ws;                                   // 512 KB
  float* wsmin = (float*)(ws + (size_t)512 * 1024);            // 2 x NPTS floats
  float* partial = (float*)(ws + (size_t)512 * 1024 + (size_t)2 * NPTS * 4);

  cpl_prep<<<NTGT / 256, 256, 0, stream>>>(targets, bfrag);
  dim3 gmain(NPTS / 256, JSPLIT);  // 512 x 2 = 1024 blocks, 4096 waves
  cpl_main<<<gmain, 256, 0, stream>>>(outputs, (const char*)bfrag, wsmin);
  cpl_reduce1<<<256, 256, 0, stream>>>(wsmin, partial);
  cpl_reduce2<<<1, 256, 0, stream>>>(partial, out);
}